// Round 16
// baseline (341.201 us; speedup 1.0000x reference)
//
#include <hip/hip_runtime.h>
#include <math.h>

// SWALP global block-quantize, R16: 3-kernel sampled-exponent + atomic verify.
//   k0: 50176 samples (every 256th float4, exact span) -> per-block max ->
//       ws2[0..195]; also clears the MG atomic word (d_ws not re-poisoned
//       between replays, so the clear keeps every call identical).
//   k1: 7168 blocks x contiguous slices (CH=7 float4/thread). e_s = bucket of
//       sample max (wave-shuffle reduce of ws2, no LDS). Quantize with e_s,
//       builtin-nt stores (no barrier before stores). Block max -> ONE
//       device-scope integer atomicMax (uint order == float order for |x|;
//       integer max is order-independent -> deterministic).
//   k2: recompute e_s, read Mg from the atomic word; bucket match -> exit
//       (P(miss) ~ e^-12.7 for N(0,1); correctness net for any input);
//       else requantize slice with e_g -> bit-exact.
// Traffic: ~3 + 205.5R (partially LLC-served, FETCH~100MB) + 205.5W.

#define NT 256
#define NB0 196                  // sample blocks: 196*256 = 50176 = n4/256
#define NB 7168                  // main blocks; NB*NT*CH == n4
#define CH 7                     // float4 per thread
#define MG_SLOT 200              // ws2 uint slot for global-max bits
#define GRID1 2048               // fallback grid

typedef float v4f __attribute__((ext_vector_type(4)));

__device__ inline int exp_floor(float m) {          // floor(log2|m|), floored at -120
    int eb = (int)((__float_as_uint(m) >> 23) & 0xff);
    int e = (eb == 0) ? -120 : eb - 127;
    return max(-120, min(127, e));
}
__device__ inline float exp2i(int k) {              // 2^k, k in [-126,127]
    return __uint_as_float((unsigned)(k + 127) << 23);
}
__device__ inline float absmax4(v4f v) {
    return fmaxf(fmaxf(fabsf(v.x), fabsf(v.y)), fmaxf(fabsf(v.z), fabsf(v.w)));
}
__device__ inline v4f quant4(v4f v, float s, float inv) {
    float a = fminf(fmaxf(rintf(v.x * s), -128.0f), 127.0f);
    float b = fminf(fmaxf(rintf(v.y * s), -128.0f), 127.0f);
    float c = fminf(fmaxf(rintf(v.z * s), -128.0f), 127.0f);
    float d = fminf(fmaxf(rintf(v.w * s), -128.0f), 127.0f);
    v4f r;
    r.x = a * inv; r.y = b * inv; r.z = c * inv; r.w = d * inv;
    return r;
}
__device__ inline float wave_max(float m) {
    #pragma unroll
    for (int off = 32; off > 0; off >>= 1)
        m = fmaxf(m, __shfl_xor(m, off, 64));
    return m;
}
__device__ inline float block_max_reduce(float m, int t) {
    __shared__ float sm[4];
    m = wave_max(m);
    if ((t & 63) == 0) sm[t >> 6] = m;
    __syncthreads();
    return fmaxf(fmaxf(sm[0], sm[1]), fmaxf(sm[2], sm[3]));
}
// sampled bound Ms from ws2[0..195] via pure-shuffle wave reduce (no LDS)
__device__ inline float sample_max(const float* ws2, int t) {
    const int lane = t & 63;
    float m = 0.0f;
    #pragma unroll
    for (int k = 0; k < 4; ++k) {
        int idx = lane + k * 64;
        if (idx < NB0) m = fmaxf(m, ws2[idx]);
    }
    return wave_max(m);
}

__global__ __launch_bounds__(NT) void bq_sample(const float* __restrict__ x,
                                                float* __restrict__ ws2) {
    const v4f* __restrict__ x4 = (const v4f*)x;
    const int gtid = blockIdx.x * NT + threadIdx.x;   // 50176 threads, exact span
    float m = absmax4(x4[(size_t)gtid << 8]);
    const float mb = block_max_reduce(m, threadIdx.x);
    if (threadIdx.x == 0) {
        ws2[blockIdx.x] = mb;
        if (blockIdx.x == 0)
            ((unsigned*)ws2)[MG_SLOT] = 0u;           // reset atomic (replay-safe)
    }
}

__global__ __launch_bounds__(NT) void bq_spec(const float* __restrict__ x,
                                              float* __restrict__ out,
                                              float* __restrict__ ws2) {
    const int t = threadIdx.x;
    const float msv = sample_max(ws2, t);
    const int es = exp_floor(msv);
    const float s = exp2i(6 - es), inv = exp2i(es - 6);

    const v4f* __restrict__ x4 = (const v4f*)x + (size_t)blockIdx.x * (NT * CH);
    v4f* __restrict__ o4 = (v4f*)out + (size_t)blockIdx.x * (NT * CH);

    float m = 0.0f;
    #pragma unroll
    for (int k = 0; k < CH; ++k) {
        v4f v = x4[k * NT + t];
        m = fmaxf(m, absmax4(v));
        __builtin_nontemporal_store(quant4(v, s, inv), &o4[k * NT + t]);
    }
    const float mb = block_max_reduce(m, t);          // after stores issued
    if (t == 0)
        atomicMax(&((unsigned*)ws2)[MG_SLOT], __float_as_uint(fmaxf(mb, msv)));
}

__global__ __launch_bounds__(NT) void bq_fix(const float* __restrict__ x,
                                             float* __restrict__ out,
                                             const float* __restrict__ ws2) {
    const int t = threadIdx.x;
    const float msv = sample_max(ws2, t);
    const int es = exp_floor(msv);
    const float mg = __uint_as_float(((const unsigned*)ws2)[MG_SLOT]);
    const int eg = exp_floor(mg);
    if (eg == es) return;                             // expected path: all exit

    const float s = exp2i(6 - eg), inv = exp2i(eg - 6);
    const v4f* __restrict__ x4 = (const v4f*)x + (size_t)blockIdx.x * (NT * CH);
    v4f* __restrict__ o4 = (v4f*)out + (size_t)blockIdx.x * (NT * CH);
    #pragma unroll
    for (int k = 0; k < CH; ++k)
        __builtin_nontemporal_store(quant4(x4[k * NT + t], s, inv), &o4[k * NT + t]);
}

// ---------------- fallback: proven R4 two-pass ----------------

__global__ __launch_bounds__(256) void bq_absmax(const float* __restrict__ x,
                                                 float* __restrict__ partial,
                                                 int n) {
    const int n4 = n >> 2;
    const v4f* __restrict__ x4 = (const v4f*)x;
    int tid = blockIdx.x * blockDim.x + threadIdx.x;
    int stride = gridDim.x * blockDim.x;
    float m = 0.0f;
    for (int i = tid; i < n4; i += stride) m = fmaxf(m, absmax4(x4[i]));
    for (int i = (n4 << 2) + tid; i < n; i += stride) m = fmaxf(m, fabsf(x[i]));
    const float mb = block_max_reduce(m, threadIdx.x);
    if (threadIdx.x == 0) partial[blockIdx.x] = mb;
}

__global__ __launch_bounds__(256) void bq_quant(const float* __restrict__ x,
                                                float* __restrict__ out,
                                                const float* __restrict__ partial,
                                                int n) {
    float bm = 0.0f;
    #pragma unroll
    for (int k = 0; k < GRID1 / 256; ++k)
        bm = fmaxf(bm, partial[threadIdx.x + k * 256]);
    const float maxe = block_max_reduce(bm, threadIdx.x);

    const int n4 = n >> 2;
    const v4f* __restrict__ x4 = (const v4f*)x;
    v4f* __restrict__ o4 = (v4f*)out;
    const int tid = blockIdx.x * blockDim.x + threadIdx.x;
    const int T = gridDim.x * blockDim.x;

    if (maxe == 0.0f) {
        for (int i = tid; i < n4; i += T)
            __builtin_nontemporal_store(x4[i], &o4[i]);
        for (int i = (n4 << 2) + tid; i < n; i += T) out[i] = x[i];
        return;
    }
    int e = ilogbf(maxe);
    e = max(-128, min(127, e));
    const float scale    = ldexpf(1.0f, -e + 6);
    const float invscale = ldexpf(1.0f, e - 6);
    for (int i = tid; i < n4; i += T)
        __builtin_nontemporal_store(quant4(x4[i], scale, invscale), &o4[i]);
    for (int i = (n4 << 2) + tid; i < n; i += T) {
        float a = rintf(x[i] * scale);
        a = fminf(fmaxf(a, -128.0f), 127.0f);
        out[i] = a * invscale;
    }
}

extern "C" void kernel_launch(void* const* d_in, const int* in_sizes, int n_in,
                              void* d_out, int out_size, void* d_ws, size_t ws_size,
                              hipStream_t stream) {
    const float* x = (const float*)d_in[0];
    float* out = (float*)d_out;
    int n = in_sizes[0];
    const int n4 = n >> 2;

    float* ws2 = (float*)d_ws;                // [0..195] sample maxes, [200] MG bits
    const size_t need = (size_t)(MG_SLOT + 8) * sizeof(float);

    if (n4 == NB * NT * CH && n4 == NB0 * NT * 256 && ws_size >= need) {
        hipLaunchKernelGGL(bq_sample, dim3(NB0), dim3(NT), 0, stream, x, ws2);
        hipLaunchKernelGGL(bq_spec,   dim3(NB),  dim3(NT), 0, stream, x, out, ws2);
        hipLaunchKernelGGL(bq_fix,    dim3(NB),  dim3(NT), 0, stream, x, out, ws2);
    } else {
        float* partial = (float*)d_ws;        // GRID1 floats
        hipLaunchKernelGGL(bq_absmax, dim3(GRID1), dim3(256), 0, stream, x, partial, n);
        hipLaunchKernelGGL(bq_quant,  dim3(GRID1), dim3(256), 0, stream, x, out, partial, n);
    }
}

// Round 17
// 109.905 us; speedup vs baseline: 3.1045x; 3.1045x over previous
//
#include <hip/hip_runtime.h>
#include <math.h>

// SWALP global block-quantize, R17: R16 with the atomic word moved to an
// ISOLATED cache line. R16's 341us regression: the device-scope atomicMax
// target (ws2[200]) shared a 128B line with ws2[192..195], which every block
// READS at start -> line ping-pong across XCD L2s serialized the kernel.
//   k0: 50176 samples (every 256th float4) -> per-block max -> ws2[0..195];
//       clears the MG word (replay-safe).
//   k1: 7168 blocks x contiguous slices (CH=7). e_s from sample maxes
//       (wave-shuffle reduce). Quantize with e_s, builtin-nt stores. Block max
//       -> one device-scope atomicMax on the ISOLATED word (uint order ==
//       float order for |x| >= 0; max is order-independent -> deterministic).
//   k2: bucket(Mg) == bucket(Ms) -> exit (P(miss) ~ e^-12.7 for N(0,1));
//       else requantize with e_g -> bit-exact. Correctness for ANY input.
// Traffic: ~3 + 205.5R (FETCH~100MB, LLC-served half) + 205.5W.

#define NT 256
#define NB0 196                  // sample blocks: 196*256 = 50176 = n4/256
#define NB 7168                  // main blocks; NB*NT*CH == n4
#define CH 7                     // float4 per thread
#define MG_SLOT 1024             // uint index: byte 4096 — own cache line, no reads nearby
#define GRID1 2048               // fallback grid

typedef float v4f __attribute__((ext_vector_type(4)));

__device__ inline int exp_floor(float m) {          // floor(log2|m|), floored at -120
    int eb = (int)((__float_as_uint(m) >> 23) & 0xff);
    int e = (eb == 0) ? -120 : eb - 127;
    return max(-120, min(127, e));
}
__device__ inline float exp2i(int k) {              // 2^k, k in [-126,127]
    return __uint_as_float((unsigned)(k + 127) << 23);
}
__device__ inline float absmax4(v4f v) {
    return fmaxf(fmaxf(fabsf(v.x), fabsf(v.y)), fmaxf(fabsf(v.z), fabsf(v.w)));
}
__device__ inline v4f quant4(v4f v, float s, float inv) {
    float a = fminf(fmaxf(rintf(v.x * s), -128.0f), 127.0f);
    float b = fminf(fmaxf(rintf(v.y * s), -128.0f), 127.0f);
    float c = fminf(fmaxf(rintf(v.z * s), -128.0f), 127.0f);
    float d = fminf(fmaxf(rintf(v.w * s), -128.0f), 127.0f);
    v4f r;
    r.x = a * inv; r.y = b * inv; r.z = c * inv; r.w = d * inv;
    return r;
}
__device__ inline float wave_max(float m) {
    #pragma unroll
    for (int off = 32; off > 0; off >>= 1)
        m = fmaxf(m, __shfl_xor(m, off, 64));
    return m;
}
__device__ inline float block_max_reduce(float m, int t) {
    __shared__ float sm[4];
    m = wave_max(m);
    if ((t & 63) == 0) sm[t >> 6] = m;
    __syncthreads();
    return fmaxf(fmaxf(sm[0], sm[1]), fmaxf(sm[2], sm[3]));
}
// sampled bound Ms from ws2[0..195] via pure-shuffle wave reduce (no LDS)
__device__ inline float sample_max(const float* ws2, int t) {
    const int lane = t & 63;
    float m = 0.0f;
    #pragma unroll
    for (int k = 0; k < 4; ++k) {
        int idx = lane + k * 64;
        if (idx < NB0) m = fmaxf(m, ws2[idx]);
    }
    return wave_max(m);
}

__global__ __launch_bounds__(NT) void bq_sample(const float* __restrict__ x,
                                                float* __restrict__ ws2) {
    const v4f* __restrict__ x4 = (const v4f*)x;
    const int gtid = blockIdx.x * NT + threadIdx.x;   // 50176 threads, exact span
    float m = absmax4(x4[(size_t)gtid << 8]);
    const float mb = block_max_reduce(m, threadIdx.x);
    if (threadIdx.x == 0) {
        ws2[blockIdx.x] = mb;
        if (blockIdx.x == 0)
            ((unsigned*)ws2)[MG_SLOT] = 0u;           // reset atomic (replay-safe)
    }
}

__global__ __launch_bounds__(NT) void bq_spec(const float* __restrict__ x,
                                              float* __restrict__ out,
                                              float* __restrict__ ws2) {
    const int t = threadIdx.x;
    const float msv = sample_max(ws2, t);
    const int es = exp_floor(msv);
    const float s = exp2i(6 - es), inv = exp2i(es - 6);

    const v4f* __restrict__ x4 = (const v4f*)x + (size_t)blockIdx.x * (NT * CH);
    v4f* __restrict__ o4 = (v4f*)out + (size_t)blockIdx.x * (NT * CH);

    float m = 0.0f;
    #pragma unroll
    for (int k = 0; k < CH; ++k) {
        v4f v = x4[k * NT + t];
        m = fmaxf(m, absmax4(v));
        __builtin_nontemporal_store(quant4(v, s, inv), &o4[k * NT + t]);
    }
    const float mb = block_max_reduce(m, t);          // after stores issued
    if (t == 0)
        atomicMax(&((unsigned*)ws2)[MG_SLOT], __float_as_uint(fmaxf(mb, msv)));
}

__global__ __launch_bounds__(NT) void bq_fix(const float* __restrict__ x,
                                             float* __restrict__ out,
                                             const float* __restrict__ ws2) {
    const int t = threadIdx.x;
    const float msv = sample_max(ws2, t);
    const int es = exp_floor(msv);
    const float mg = __uint_as_float(((const unsigned*)ws2)[MG_SLOT]);
    const int eg = exp_floor(mg);
    if (eg == es) return;                             // expected path: all exit

    const float s = exp2i(6 - eg), inv = exp2i(eg - 6);
    const v4f* __restrict__ x4 = (const v4f*)x + (size_t)blockIdx.x * (NT * CH);
    v4f* __restrict__ o4 = (v4f*)out + (size_t)blockIdx.x * (NT * CH);
    #pragma unroll
    for (int k = 0; k < CH; ++k)
        __builtin_nontemporal_store(quant4(x4[k * NT + t], s, inv), &o4[k * NT + t]);
}

// ---------------- fallback: proven R4 two-pass ----------------

__global__ __launch_bounds__(256) void bq_absmax(const float* __restrict__ x,
                                                 float* __restrict__ partial,
                                                 int n) {
    const int n4 = n >> 2;
    const v4f* __restrict__ x4 = (const v4f*)x;
    int tid = blockIdx.x * blockDim.x + threadIdx.x;
    int stride = gridDim.x * blockDim.x;
    float m = 0.0f;
    for (int i = tid; i < n4; i += stride) m = fmaxf(m, absmax4(x4[i]));
    for (int i = (n4 << 2) + tid; i < n; i += stride) m = fmaxf(m, fabsf(x[i]));
    const float mb = block_max_reduce(m, threadIdx.x);
    if (threadIdx.x == 0) partial[blockIdx.x] = mb;
}

__global__ __launch_bounds__(256) void bq_quant(const float* __restrict__ x,
                                                float* __restrict__ out,
                                                const float* __restrict__ partial,
                                                int n) {
    float bm = 0.0f;
    #pragma unroll
    for (int k = 0; k < GRID1 / 256; ++k)
        bm = fmaxf(bm, partial[threadIdx.x + k * 256]);
    const float maxe = block_max_reduce(bm, threadIdx.x);

    const int n4 = n >> 2;
    const v4f* __restrict__ x4 = (const v4f*)x;
    v4f* __restrict__ o4 = (v4f*)out;
    const int tid = blockIdx.x * blockDim.x + threadIdx.x;
    const int T = gridDim.x * blockDim.x;

    if (maxe == 0.0f) {
        for (int i = tid; i < n4; i += T)
            __builtin_nontemporal_store(x4[i], &o4[i]);
        for (int i = (n4 << 2) + tid; i < n; i += T) out[i] = x[i];
        return;
    }
    int e = ilogbf(maxe);
    e = max(-128, min(127, e));
    const float scale    = ldexpf(1.0f, -e + 6);
    const float invscale = ldexpf(1.0f, e - 6);
    for (int i = tid; i < n4; i += T)
        __builtin_nontemporal_store(quant4(x4[i], scale, invscale), &o4[i]);
    for (int i = (n4 << 2) + tid; i < n; i += T) {
        float a = rintf(x[i] * scale);
        a = fminf(fmaxf(a, -128.0f), 127.0f);
        out[i] = a * invscale;
    }
}

extern "C" void kernel_launch(void* const* d_in, const int* in_sizes, int n_in,
                              void* d_out, int out_size, void* d_ws, size_t ws_size,
                              hipStream_t stream) {
    const float* x = (const float*)d_in[0];
    float* out = (float*)d_out;
    int n = in_sizes[0];
    const int n4 = n >> 2;

    float* ws2 = (float*)d_ws;   // [0..195] sample maxes; uint[1024] = MG bits (own line)
    const size_t need = (size_t)(MG_SLOT + 32) * sizeof(float);

    if (n4 == NB * NT * CH && n4 == NB0 * NT * 256 && ws_size >= need) {
        hipLaunchKernelGGL(bq_sample, dim3(NB0), dim3(NT), 0, stream, x, ws2);
        hipLaunchKernelGGL(bq_spec,   dim3(NB),  dim3(NT), 0, stream, x, out, ws2);
        hipLaunchKernelGGL(bq_fix,    dim3(NB),  dim3(NT), 0, stream, x, out, ws2);
    } else {
        float* partial = (float*)d_ws;        // GRID1 floats
        hipLaunchKernelGGL(bq_absmax, dim3(GRID1), dim3(256), 0, stream, x, partial, n);
        hipLaunchKernelGGL(bq_quant,  dim3(GRID1), dim3(256), 0, stream, x, out, partial, n);
    }
}

// Round 18
// 74.296 us; speedup vs baseline: 4.5925x; 1.4793x over previous
//
#include <hip/hip_runtime.h>
#include <math.h>

// SWALP global block-quantize, R18 = R13 (best, 73.87us) + forced burst k1.
//   Single change vs R13: bq_spec/bq_fix drop __restrict__ on x/out, so stores
//   may alias loads -> compiler MUST buffer v[7] in regs (R13's VGPR=20 showed
//   it rematerialized loads, interleaving R/W at 16B granularity; now the wave
//   issues a 7KB read burst, then a 7KB write burst -> better DRAM scheduling).
//   k0: 50176 samples (every 256th float4) -> per-block max -> ws2[0..195].
//   k1: 7168 blocks x contiguous slices (CH=7). partial[b] = max(block max, Ms);
//       quantize with bucket(partial[b]) (== bucket(Mg) w.h.p.), nt stores.
//   k2a: 1 block reduces partial[7168] -> Mg -> ws2[MG_SLOT].
//   k2b: per-block: bucket(partial[b]) == bucket(Mg) -> exit (expected all);
//        else requantize from x with e_g -> bit-exact. Deterministic.

#define NT 256
#define NB0 196                  // sample blocks: 196*256 = 50176 = n4/256
#define NB 7168                  // spec blocks; NB*NT*CH == n4
#define CH 7                     // float4 per thread
#define MG_SLOT (NB0 + 4)        // ws2 slot for global max
#define GRID1 2048               // fallback grid

typedef float v4f __attribute__((ext_vector_type(4)));

__device__ inline int exp_floor(float m) {          // floor(log2|m|), floored at -120
    int eb = (int)((__float_as_uint(m) >> 23) & 0xff);
    int e = (eb == 0) ? -120 : eb - 127;
    return max(-120, min(127, e));
}
__device__ inline float exp2i(int k) {              // 2^k, k in [-126,127]
    return __uint_as_float((unsigned)(k + 127) << 23);
}
__device__ inline float absmax4(v4f v) {
    return fmaxf(fmaxf(fabsf(v.x), fabsf(v.y)), fmaxf(fabsf(v.z), fabsf(v.w)));
}
__device__ inline v4f quant4(v4f v, float s, float inv) {
    float a = fminf(fmaxf(rintf(v.x * s), -128.0f), 127.0f);
    float b = fminf(fmaxf(rintf(v.y * s), -128.0f), 127.0f);
    float c = fminf(fmaxf(rintf(v.z * s), -128.0f), 127.0f);
    float d = fminf(fmaxf(rintf(v.w * s), -128.0f), 127.0f);
    v4f r;
    r.x = a * inv; r.y = b * inv; r.z = c * inv; r.w = d * inv;
    return r;
}
__device__ inline float block_max_reduce(float m, int t) {
    __shared__ float sm[4];
    __syncthreads();                                 // safe for repeated use
    #pragma unroll
    for (int off = 32; off > 0; off >>= 1)
        m = fmaxf(m, __shfl_xor(m, off, 64));
    if ((t & 63) == 0) sm[t >> 6] = m;
    __syncthreads();
    return fmaxf(fmaxf(sm[0], sm[1]), fmaxf(sm[2], sm[3]));
}

__global__ __launch_bounds__(NT) void bq_sample(const float* __restrict__ x,
                                                float* __restrict__ ws2) {
    const v4f* __restrict__ x4 = (const v4f*)x;
    const int gtid = blockIdx.x * NT + threadIdx.x;   // 50176 threads, exact span
    float m = absmax4(x4[(size_t)gtid << 8]);
    const float mb = block_max_reduce(m, threadIdx.x);
    if (threadIdx.x == 0) ws2[blockIdx.x] = mb;
}

// NOTE: x/out deliberately NOT __restrict__ -> stores may alias loads ->
// compiler must buffer v[CH] before the first store (burst R, then burst W).
__global__ __launch_bounds__(NT) void bq_spec(const float* x,
                                              float* out,
                                              float* __restrict__ partial,
                                              const float* __restrict__ ws2) {
    const v4f* x4 = (const v4f*)x + (size_t)blockIdx.x * (NT * CH);
    v4f* o4 = (v4f*)out + (size_t)blockIdx.x * (NT * CH);
    const int t = threadIdx.x;

    v4f v[CH];
    #pragma unroll
    for (int k = 0; k < CH; ++k)
        v[k] = x4[k * NT + t];

    float m = (t < NB0) ? ws2[t] : 0.0f;   // merge sampled bound Ms
    #pragma unroll
    for (int k = 0; k < CH; ++k)
        m = fmaxf(m, absmax4(v[k]));
    const float mb = block_max_reduce(m, t);   // = max(block max, Ms)
    if (t == 0) partial[blockIdx.x] = mb;

    const int e = exp_floor(mb);
    const float s = exp2i(6 - e), inv = exp2i(e - 6);
    #pragma unroll
    for (int k = 0; k < CH; ++k)
        __builtin_nontemporal_store(quant4(v[k], s, inv), &o4[k * NT + t]);
}

__global__ __launch_bounds__(NT) void bq_redmax(const float* __restrict__ partial,
                                                float* __restrict__ ws2) {
    const int t = threadIdx.x;
    float g = 0.0f;
    #pragma unroll
    for (int k = 0; k < NB / NT; ++k)
        g = fmaxf(g, partial[t + k * NT]);
    const float mg = block_max_reduce(g, t);
    if (t == 0) ws2[MG_SLOT] = mg;
}

__global__ __launch_bounds__(NT) void bq_fix(const float* x,
                                             float* out,
                                             const float* __restrict__ partial,
                                             const float* __restrict__ ws2) {
    const int eg = exp_floor(ws2[MG_SLOT]);            // L2 broadcast scalar
    if (exp_floor(partial[blockIdx.x]) == eg) return;  // uniform exit (expected: all)

    const int t = threadIdx.x;
    const v4f* x4 = (const v4f*)x + (size_t)blockIdx.x * (NT * CH);
    v4f* o4 = (v4f*)out + (size_t)blockIdx.x * (NT * CH);
    const float s = exp2i(6 - eg), inv = exp2i(eg - 6);
    v4f v[CH];
    #pragma unroll
    for (int k = 0; k < CH; ++k)
        v[k] = x4[k * NT + t];
    #pragma unroll
    for (int k = 0; k < CH; ++k)
        __builtin_nontemporal_store(quant4(v[k], s, inv), &o4[k * NT + t]);
}

// ---------------- fallback: proven R4 two-pass ----------------

__global__ __launch_bounds__(256) void bq_absmax(const float* __restrict__ x,
                                                 float* __restrict__ partial,
                                                 int n) {
    const int n4 = n >> 2;
    const v4f* __restrict__ x4 = (const v4f*)x;
    int tid = blockIdx.x * blockDim.x + threadIdx.x;
    int stride = gridDim.x * blockDim.x;
    float m = 0.0f;
    for (int i = tid; i < n4; i += stride) m = fmaxf(m, absmax4(x4[i]));
    for (int i = (n4 << 2) + tid; i < n; i += stride) m = fmaxf(m, fabsf(x[i]));
    const float mb = block_max_reduce(m, threadIdx.x);
    if (threadIdx.x == 0) partial[blockIdx.x] = mb;
}

__global__ __launch_bounds__(256) void bq_quant(const float* __restrict__ x,
                                                float* __restrict__ out,
                                                const float* __restrict__ partial,
                                                int n) {
    float bm = 0.0f;
    #pragma unroll
    for (int k = 0; k < GRID1 / 256; ++k)
        bm = fmaxf(bm, partial[threadIdx.x + k * 256]);
    const float maxe = block_max_reduce(bm, threadIdx.x);

    const int n4 = n >> 2;
    const v4f* __restrict__ x4 = (const v4f*)x;
    v4f* __restrict__ o4 = (v4f*)out;
    const int tid = blockIdx.x * blockDim.x + threadIdx.x;
    const int T = gridDim.x * blockDim.x;

    if (maxe == 0.0f) {
        for (int i = tid; i < n4; i += T)
            __builtin_nontemporal_store(x4[i], &o4[i]);
        for (int i = (n4 << 2) + tid; i < n; i += T) out[i] = x[i];
        return;
    }
    int e = ilogbf(maxe);
    e = max(-128, min(127, e));
    const float scale    = ldexpf(1.0f, -e + 6);
    const float invscale = ldexpf(1.0f, e - 6);
    for (int i = tid; i < n4; i += T)
        __builtin_nontemporal_store(quant4(x4[i], scale, invscale), &o4[i]);
    for (int i = (n4 << 2) + tid; i < n; i += T) {
        float a = rintf(x[i] * scale);
        a = fminf(fmaxf(a, -128.0f), 127.0f);
        out[i] = a * invscale;
    }
}

extern "C" void kernel_launch(void* const* d_in, const int* in_sizes, int n_in,
                              void* d_out, int out_size, void* d_ws, size_t ws_size,
                              hipStream_t stream) {
    const float* x = (const float*)d_in[0];
    float* out = (float*)d_out;
    int n = in_sizes[0];
    const int n4 = n >> 2;

    // ws layout: [partial: NB floats][ws2: NB0+8 floats]
    float* partial = (float*)d_ws;
    float* ws2 = partial + NB;
    const size_t need = (size_t)(NB + MG_SLOT + 8) * sizeof(float);

    if (n4 == NB * NT * CH && n4 == NB0 * NT * 256 && ws_size >= need) {
        hipLaunchKernelGGL(bq_sample, dim3(NB0), dim3(NT), 0, stream, x, ws2);
        hipLaunchKernelGGL(bq_spec,   dim3(NB),  dim3(NT), 0, stream, x, out, partial, ws2);
        hipLaunchKernelGGL(bq_redmax, dim3(1),   dim3(NT), 0, stream, partial, ws2);
        hipLaunchKernelGGL(bq_fix,    dim3(NB),  dim3(NT), 0, stream, x, out, partial, ws2);
    } else {
        hipLaunchKernelGGL(bq_absmax, dim3(GRID1), dim3(256), 0, stream, x, partial, n);
        hipLaunchKernelGGL(bq_quant,  dim3(GRID1), dim3(256), 0, stream, x, out, partial, n);
    }
}